// Round 3
// baseline (281.446 us; speedup 1.0000x reference)
//
#include <hip/hip_runtime.h>

// ---------------- problem constants ----------------
#define DIM     384
#define QKV_CH  1152          // 3*DIM
#define HD      32            // head dim
#define CD      128           // channels per dilation group (4 heads)
#define BATCH   4
#define SEQ     8192
#define ROWS    (BATCH*SEQ)   // 32768
#define SCALE   0.17677669529663687f   // 32^-0.5

typedef short bf16x8 __attribute__((ext_vector_type(8)));
typedef float f32x4  __attribute__((ext_vector_type(4)));

__device__ __forceinline__ unsigned short f2bf(float f) {
  unsigned int u = __float_as_uint(f);
  u += 0x7fffu + ((u >> 16) & 1u);      // RNE
  return (unsigned short)(u >> 16);
}
__device__ __forceinline__ float bf2f(unsigned short b) {
  return __uint_as_float(((unsigned int)b) << 16);
}
__device__ __forceinline__ void unpack8(uint4 u, float* f) {
  f[0] = bf2f((unsigned short)(u.x & 0xffffu)); f[1] = bf2f((unsigned short)(u.x >> 16));
  f[2] = bf2f((unsigned short)(u.y & 0xffffu)); f[3] = bf2f((unsigned short)(u.y >> 16));
  f[4] = bf2f((unsigned short)(u.z & 0xffffu)); f[5] = bf2f((unsigned short)(u.z >> 16));
  f[6] = bf2f((unsigned short)(u.w & 0xffffu)); f[7] = bf2f((unsigned short)(u.w >> 16));
}

// ---------------- fp32 -> bf16 convert ----------------
__global__ __launch_bounds__(256) void cvt_f32_bf16(const float* __restrict__ in,
                                                    unsigned short* __restrict__ out,
                                                    int n4) {
  int i = blockIdx.x * 256 + threadIdx.x;
  if (i >= n4) return;
  float4 v = ((const float4*)in)[i];
  ushort4 o;
  o.x = f2bf(v.x); o.y = f2bf(v.y); o.z = f2bf(v.z); o.w = f2bf(v.w);
  ((ushort4*)out)[i] = o;
}

// ---------------- bf16 MFMA GEMM (register-direct, no LDS, no barriers) ----------------
// C[M,NT] = A[M,K] * Bt[NT,K]^T + bias.  128x128 tile per block, 4 waves, each wave an
// independent 64x64 quadrant (4x4 MFMA tiles). MFMA fragments are 8 consecutive
// K-elements = one 16B global load per lane, so both operands load DIRECTLY from
// global (L1/L2/L3-cached) into VGPRs. Zero __syncthreads -> no vmcnt(0) barrier
// drain; the fully-unrolled 12-iter K-loop lets the compiler interleave MFMA with
// loads under fine-grained vmcnt (AITER-style).
// Swapped operands: mfma(b_frag, a_frag) -> lane's 4 acc regs = 4 consecutive output
// columns -> packed 8B (bf16) / 16B (fp32) stores.
template<int OUT_BF16, int K, int NT>
__global__ __launch_bounds__(256) void gemm_bt(const unsigned short* __restrict__ A,
                                               const unsigned short* __restrict__ Bt,
                                               const float* __restrict__ bias,
                                               void* __restrict__ Cv) {
  const int t = threadIdx.x;
  const int wave = t >> 6, lane = t & 63;
  const int quad = lane >> 4, l16 = lane & 15;
  const int row0 = blockIdx.x * 128, col0 = blockIdx.y * 128;
  const int wm = (wave & 1) * 64, wn = (wave >> 1) * 64;

  // base pointers: lane's fragment row, first 16B chunk (quad*8 elems into K)
  const unsigned short* Ab[4];
  const unsigned short* Bb[4];
#pragma unroll
  for (int mi = 0; mi < 4; ++mi)
    Ab[mi] = A + (size_t)(row0 + wm + mi * 16 + l16) * K + quad * 8;
#pragma unroll
  for (int ni = 0; ni < 4; ++ni)
    Bb[ni] = Bt + (size_t)(col0 + wn + ni * 16 + l16) * K + quad * 8;

  f32x4 acc[4][4] = {};

#pragma unroll
  for (int kk = 0; kk < K / 32; ++kk) {
    bf16x8 af[4], bfv[4];
#pragma unroll
    for (int mi = 0; mi < 4; ++mi) af[mi]  = *(const bf16x8*)(Ab[mi] + kk * 32);
#pragma unroll
    for (int ni = 0; ni < 4; ++ni) bfv[ni] = *(const bf16x8*)(Bb[ni] + kk * 32);
#pragma unroll
    for (int mi = 0; mi < 4; ++mi)
#pragma unroll
      for (int ni = 0; ni < 4; ++ni)
        acc[mi][ni] = __builtin_amdgcn_mfma_f32_16x16x32_bf16(bfv[ni], af[mi], acc[mi][ni], 0, 0, 0);
  }

  // epilogue: lane owns output row gr = row-index l16; regs = 4 consecutive cols
  float4 bv[4];
#pragma unroll
  for (int ni = 0; ni < 4; ++ni)
    bv[ni] = *(const float4*)&bias[col0 + wn + ni * 16 + quad * 4];

#pragma unroll
  for (int mi = 0; mi < 4; ++mi) {
    size_t gr = (size_t)(row0 + wm + mi * 16 + l16);
#pragma unroll
    for (int ni = 0; ni < 4; ++ni) {
      int gc = col0 + wn + ni * 16 + quad * 4;
      float v0 = acc[mi][ni][0] + bv[ni].x;
      float v1 = acc[mi][ni][1] + bv[ni].y;
      float v2 = acc[mi][ni][2] + bv[ni].z;
      float v3 = acc[mi][ni][3] + bv[ni].w;
      if (OUT_BF16) {
        uint2 u;
        u.x = (unsigned int)f2bf(v0) | ((unsigned int)f2bf(v1) << 16);
        u.y = (unsigned int)f2bf(v2) | ((unsigned int)f2bf(v3) << 16);
        *(uint2*)&((unsigned short*)Cv)[gr * NT + gc] = u;
      } else {
        float4 o; o.x = v0; o.y = v1; o.z = v2; o.w = v3;
        *(float4*)&((float*)Cv)[gr * NT + gc] = o;
      }
    }
  }
}

// ---------------- dilated local attention ----------------
// qkv: bf16 [ROWS, 1152], channel = s*384 + d*128 + h*32 + e
// out: bf16 [ROWS, 384],  channel = d*128 + h*32 + e
// One thread per (row i, dilation d, head h). 3 taps at offsets {-dil,0,+dil};
// softmax denominator gets +6 from the six structural zero taps (exp(0) each).
__global__ __launch_bounds__(256) void attn_kernel(const unsigned short* __restrict__ qkv,
                                                   unsigned short* __restrict__ out) {
  int tid = blockIdx.x * 256 + threadIdx.x;   // [0, ROWS*12)
  int i  = tid / 12;
  int dh = tid - i * 12;
  int d = dh >> 2, h = dh & 3;
  int dil = d + 1;
  int n = i & (SEQ - 1);
  size_t base = (size_t)i * QKV_CH + d * CD + h * HD;

  float q[32];
  {
    const uint4* qp = (const uint4*)(qkv + base);
#pragma unroll
    for (int c = 0; c < 4; ++c) unpack8(qp[c], &q[c * 8]);
  }

  float ex[3];
  int   valid[3];
#pragma unroll
  for (int kh = 0; kh < 3; ++kh) {
    int off = (kh - 1) * dil;
    int nn = n + off;
    int v = (nn >= 0) && (nn < SEQ);
    valid[kh] = v;
    float l = 0.f;
    if (v) {
      const uint4* kp = (const uint4*)(qkv + base + DIM + (ptrdiff_t)off * QKV_CH);
#pragma unroll
      for (int c = 0; c < 4; ++c) {
        float kk[8]; unpack8(kp[c], kk);
#pragma unroll
        for (int j = 0; j < 8; ++j) l += q[c * 8 + j] * kk[j];
      }
    }
    ex[kh] = __expf(l * SCALE);   // OOR -> l=0 -> exp=1 (matches zero-padded key)
  }
  float inv = 1.f / (ex[0] + ex[1] + ex[2] + 6.f);

  float o[32];
#pragma unroll
  for (int e = 0; e < 32; ++e) o[e] = 0.f;
#pragma unroll
  for (int kh = 0; kh < 3; ++kh) {
    if (!valid[kh]) continue;
    int off = (kh - 1) * dil;
    const uint4* vp = (const uint4*)(qkv + base + 2 * DIM + (ptrdiff_t)off * QKV_CH);
    float w = ex[kh];
#pragma unroll
    for (int c = 0; c < 4; ++c) {
      float vv[8]; unpack8(vp[c], vv);
#pragma unroll
      for (int j = 0; j < 8; ++j) o[c * 8 + j] += w * vv[j];
    }
  }

  unsigned short* op = out + (size_t)i * DIM + d * CD + h * HD;
#pragma unroll
  for (int c = 0; c < 4; ++c) {
    unsigned int w0 = (unsigned int)f2bf(o[c*8+0] * inv) | ((unsigned int)f2bf(o[c*8+1] * inv) << 16);
    unsigned int w1 = (unsigned int)f2bf(o[c*8+2] * inv) | ((unsigned int)f2bf(o[c*8+3] * inv) << 16);
    unsigned int w2 = (unsigned int)f2bf(o[c*8+4] * inv) | ((unsigned int)f2bf(o[c*8+5] * inv) << 16);
    unsigned int w3 = (unsigned int)f2bf(o[c*8+6] * inv) | ((unsigned int)f2bf(o[c*8+7] * inv) << 16);
    uint4 u; u.x = w0; u.y = w1; u.z = w2; u.w = w3;
    ((uint4*)op)[c] = u;
  }
}

// ---------------- launch ----------------
extern "C" void kernel_launch(void* const* d_in, const int* in_sizes, int n_in,
                              void* d_out, int out_size, void* d_ws, size_t ws_size,
                              hipStream_t stream) {
  const float* x     = (const float*)d_in[0];
  const float* Wqkv  = (const float*)d_in[1];
  const float* bqkv  = (const float*)d_in[2];
  const float* Wproj = (const float*)d_in[3];
  const float* bproj = (const float*)d_in[4];
  float* out = (float*)d_out;

  char* ws = (char*)d_ws;
  // byte offsets (256-aligned); total ~127 MB
  unsigned short* qkv_bf   = (unsigned short*)(ws);                 // 75,497,472 B
  unsigned short* x_bf     = (unsigned short*)(ws + 75497472);      // 25,165,824 B
  unsigned short* attn_bf  = (unsigned short*)(ws + 100663296);     // 25,165,824 B
  unsigned short* wqkv_bf  = (unsigned short*)(ws + 125829120);     //    884,736 B
  unsigned short* wproj_bf = (unsigned short*)(ws + 126713856);     //    294,912 B

  // converts
  cvt_f32_bf16<<<(ROWS * DIM / 4) / 256, 256, 0, stream>>>(x, x_bf, ROWS * DIM / 4);
  cvt_f32_bf16<<<(QKV_CH * DIM / 4 + 255) / 256, 256, 0, stream>>>(Wqkv, wqkv_bf, QKV_CH * DIM / 4);
  cvt_f32_bf16<<<(DIM * DIM / 4 + 255) / 256, 256, 0, stream>>>(Wproj, wproj_bf, DIM * DIM / 4);

  // qkv = x @ Wqkv^T + bqkv   (bf16 out)
  gemm_bt<1, DIM, QKV_CH><<<dim3(ROWS / 128, QKV_CH / 128), 256, 0, stream>>>(
      x_bf, wqkv_bf, bqkv, (void*)qkv_bf);

  // dilated attention
  attn_kernel<<<(ROWS * 12) / 256, 256, 0, stream>>>(qkv_bf, attn_bf);

  // out = attn @ Wproj^T + bproj  (fp32 out)
  gemm_bt<0, DIM, DIM><<<dim3(ROWS / 128, DIM / 128), 256, 0, stream>>>(
      attn_bf, wproj_bf, bproj, (void*)out);
}

// Round 4
// 211.507 us; speedup vs baseline: 1.3307x; 1.3307x over previous
//
#include <hip/hip_runtime.h>

// ---------------- problem constants ----------------
#define DIM     384
#define QKV_CH  1152          // 3*DIM
#define HD      32            // head dim
#define CD      128           // channels per dilation group (4 heads)
#define BATCH   4
#define SEQ     8192
#define ROWS    (BATCH*SEQ)   // 32768
#define SCALE   0.17677669529663687f   // 32^-0.5

typedef short bf16x8 __attribute__((ext_vector_type(8)));
typedef float f32x4  __attribute__((ext_vector_type(4)));

__device__ __forceinline__ unsigned short f2bf(float f) {
  unsigned int u = __float_as_uint(f);
  u += 0x7fffu + ((u >> 16) & 1u);      // RNE
  return (unsigned short)(u >> 16);
}
__device__ __forceinline__ float bf2f(unsigned short b) {
  return __uint_as_float(((unsigned int)b) << 16);
}
__device__ __forceinline__ void unpack8(uint4 u, float* f) {
  f[0] = bf2f((unsigned short)(u.x & 0xffffu)); f[1] = bf2f((unsigned short)(u.x >> 16));
  f[2] = bf2f((unsigned short)(u.y & 0xffffu)); f[3] = bf2f((unsigned short)(u.y >> 16));
  f[4] = bf2f((unsigned short)(u.z & 0xffffu)); f[5] = bf2f((unsigned short)(u.z >> 16));
  f[6] = bf2f((unsigned short)(u.w & 0xffffu)); f[7] = bf2f((unsigned short)(u.w >> 16));
}

// ================= swizzled (fragment-major) layout =================
// swz(r,k; K) = ((r/16)*(K/8) + k/8)*128 + (r%16)*8 + (k%8)
// A wave's mfma fragment (16 rows x 8 consecutive k, per quad) is then
// base + lane*8 shorts -> one fully-coalesced 1KB wave load.

// ---------------- fp32 -> swizzled bf16 convert ----------------
// one thread per 8-elem chunk; chunk id == swizzled chunk index.
template<int K>
__global__ __launch_bounds__(256) void cvt_swz(const float* __restrict__ in,
                                               unsigned short* __restrict__ out) {
  const int KB = K / 8;
  int cid = blockIdx.x * 256 + threadIdx.x;
  int rl = cid & 15;
  int q  = cid >> 4;
  int rb = q / KB;
  int kb = q - rb * KB;
  const float* p = in + (size_t)(rb * 16 + rl) * K + kb * 8;
  float4 a = *(const float4*)p;
  float4 b = *(const float4*)(p + 4);
  unsigned int w0 = (unsigned int)f2bf(a.x) | ((unsigned int)f2bf(a.y) << 16);
  unsigned int w1 = (unsigned int)f2bf(a.z) | ((unsigned int)f2bf(a.w) << 16);
  unsigned int w2 = (unsigned int)f2bf(b.x) | ((unsigned int)f2bf(b.y) << 16);
  unsigned int w3 = (unsigned int)f2bf(b.z) | ((unsigned int)f2bf(b.w) << 16);
  uint4 u; u.x = w0; u.y = w1; u.z = w2; u.w = w3;
  *(uint4*)(out + (size_t)cid * 8) = u;
}

// ---------------- bf16 MFMA GEMM (register-direct, swizzled inputs) ----------------
// C[M,NT] = A[M,K] * Bt[NT,K]^T + bias, A and Bt in swizzled layout.
// 128x128 tile per block, 4 waves, each wave an independent 64x64 quadrant.
// No LDS, no __syncthreads -> no barrier drain; all loads are base+lane*16B
// fully-coalesced 1KB wave loads; 12-iter K-loop fully unrolled so the
// compiler interleaves MFMA with loads under fine-grained vmcnt.
// Swapped operands: mfma(b_frag, a_frag) -> lane's 4 acc regs = 4 consecutive
// output columns -> packed 8B (bf16) / 16B (fp32) stores.
template<int OUT_BF16, int K, int NT>
__global__ __launch_bounds__(256) void gemm_swz(const unsigned short* __restrict__ A,
                                                const unsigned short* __restrict__ Bt,
                                                const float* __restrict__ bias,
                                                void* __restrict__ Cv) {
  const int KB = K / 8;
  const int t = threadIdx.x;
  const int wave = t >> 6, lane = t & 63;
  const int quad = lane >> 4, l16 = lane & 15;
  const int row0 = blockIdx.x * 128, col0 = blockIdx.y * 128;
  const int wm = (wave & 1) * 64, wn = (wave >> 1) * 64;

  const unsigned short* PA[4];
  const unsigned short* PB[4];
#pragma unroll
  for (int mi = 0; mi < 4; ++mi)
    PA[mi] = A + (size_t)(((row0 + wm) >> 4) + mi) * KB * 128 + lane * 8;
#pragma unroll
  for (int ni = 0; ni < 4; ++ni)
    PB[ni] = Bt + (size_t)(((col0 + wn) >> 4) + ni) * KB * 128 + lane * 8;

  f32x4 acc[4][4] = {};

#pragma unroll
  for (int kk = 0; kk < K / 32; ++kk) {
    bf16x8 af[4], bfv[4];
#pragma unroll
    for (int mi = 0; mi < 4; ++mi) af[mi]  = *(const bf16x8*)(PA[mi] + kk * 512);
#pragma unroll
    for (int ni = 0; ni < 4; ++ni) bfv[ni] = *(const bf16x8*)(PB[ni] + kk * 512);
#pragma unroll
    for (int mi = 0; mi < 4; ++mi)
#pragma unroll
      for (int ni = 0; ni < 4; ++ni)
        acc[mi][ni] = __builtin_amdgcn_mfma_f32_16x16x32_bf16(bfv[ni], af[mi], acc[mi][ni], 0, 0, 0);
  }

  // epilogue: lane owns output row gr; regs = 4 consecutive cols
  float4 bv[4];
#pragma unroll
  for (int ni = 0; ni < 4; ++ni)
    bv[ni] = *(const float4*)&bias[col0 + wn + ni * 16 + quad * 4];

#pragma unroll
  for (int mi = 0; mi < 4; ++mi) {
    size_t gr = (size_t)(row0 + wm + mi * 16 + l16);
#pragma unroll
    for (int ni = 0; ni < 4; ++ni) {
      int gc = col0 + wn + ni * 16 + quad * 4;
      float v0 = acc[mi][ni][0] + bv[ni].x;
      float v1 = acc[mi][ni][1] + bv[ni].y;
      float v2 = acc[mi][ni][2] + bv[ni].z;
      float v3 = acc[mi][ni][3] + bv[ni].w;
      if (OUT_BF16) {
        uint2 u;
        u.x = (unsigned int)f2bf(v0) | ((unsigned int)f2bf(v1) << 16);
        u.y = (unsigned int)f2bf(v2) | ((unsigned int)f2bf(v3) << 16);
        *(uint2*)&((unsigned short*)Cv)[gr * NT + gc] = u;
      } else {
        float4 o; o.x = v0; o.y = v1; o.z = v2; o.w = v3;
        *(float4*)&((float*)Cv)[gr * NT + gc] = o;
      }
    }
  }
}

// ---------------- dilated local attention (swizzled output) ----------------
// qkv: bf16 [ROWS, 1152] row-major, channel = s*384 + d*128 + h*32 + e
// out: swizzled bf16 [ROWS, 384]
// Block = 192 threads = 16 rows x 12 (d,h); block b owns row-block rb=b exactly.
// Results staged in padded LDS, then written out fully coalesced in swizzled order.
__global__ __launch_bounds__(192) void attn_kernel(const unsigned short* __restrict__ qkv,
                                                   unsigned short* __restrict__ out) {
  __shared__ unsigned short smem[16 * 392];   // row stride 392 shorts: 2-way banks only
  const int t = threadIdx.x;
  const int rl = t & 15, dh = t >> 4;         // dh in [0,12)
  const int d = dh >> 2, h = dh & 3;
  const int dil = d + 1;
  const int i = blockIdx.x * 16 + rl;
  const int n = i & (SEQ - 1);
  size_t base = (size_t)i * QKV_CH + d * CD + h * HD;

  float q[32];
  {
    const uint4* qp = (const uint4*)(qkv + base);
#pragma unroll
    for (int c = 0; c < 4; ++c) unpack8(qp[c], &q[c * 8]);
  }

  float ex[3];
  int   valid[3];
#pragma unroll
  for (int kh = 0; kh < 3; ++kh) {
    int off = (kh - 1) * dil;
    int nn = n + off;
    int v = (nn >= 0) && (nn < SEQ);
    valid[kh] = v;
    float l = 0.f;
    if (v) {
      const uint4* kp = (const uint4*)(qkv + base + DIM + (ptrdiff_t)off * QKV_CH);
#pragma unroll
      for (int c = 0; c < 4; ++c) {
        float kk[8]; unpack8(kp[c], kk);
#pragma unroll
        for (int j = 0; j < 8; ++j) l += q[c * 8 + j] * kk[j];
      }
    }
    ex[kh] = __expf(l * SCALE);   // OOR -> l=0 -> exp=1 (matches zero-padded key)
  }
  float inv = 1.f / (ex[0] + ex[1] + ex[2] + 6.f);

  float o[32];
#pragma unroll
  for (int e = 0; e < 32; ++e) o[e] = 0.f;
#pragma unroll
  for (int kh = 0; kh < 3; ++kh) {
    if (!valid[kh]) continue;
    int off = (kh - 1) * dil;
    const uint4* vp = (const uint4*)(qkv + base + 2 * DIM + (ptrdiff_t)off * QKV_CH);
    float w = ex[kh];
#pragma unroll
    for (int c = 0; c < 4; ++c) {
      float vv[8]; unpack8(vp[c], vv);
#pragma unroll
      for (int j = 0; j < 8; ++j) o[c * 8 + j] += w * vv[j];
    }
  }

  // stage this thread's 32 channels into LDS
  unsigned short* sp = smem + rl * 392 + d * CD + h * HD;
#pragma unroll
  for (int c = 0; c < 4; ++c) {
    unsigned int w0 = (unsigned int)f2bf(o[c*8+0] * inv) | ((unsigned int)f2bf(o[c*8+1] * inv) << 16);
    unsigned int w1 = (unsigned int)f2bf(o[c*8+2] * inv) | ((unsigned int)f2bf(o[c*8+3] * inv) << 16);
    unsigned int w2 = (unsigned int)f2bf(o[c*8+4] * inv) | ((unsigned int)f2bf(o[c*8+5] * inv) << 16);
    unsigned int w3 = (unsigned int)f2bf(o[c*8+6] * inv) | ((unsigned int)f2bf(o[c*8+7] * inv) << 16);
    uint4 u; u.x = w0; u.y = w1; u.z = w2; u.w = w3;
    *(uint4*)(sp + c * 8) = u;
  }
  __syncthreads();

  // coalesced swizzled writes: chunk cc = kb*16 + rl', out addr = blk_base + cc*8
  unsigned short* ob = out + (size_t)blockIdx.x * (16 * DIM);
#pragma unroll
  for (int j = 0; j < 4; ++j) {
    int cc = t + j * 192;           // [0, 768)
    int kb = cc >> 4, rlp = cc & 15;
    uint4 u = *(const uint4*)(smem + rlp * 392 + kb * 8);
    *(uint4*)(ob + cc * 8) = u;
  }
}

// ---------------- launch ----------------
extern "C" void kernel_launch(void* const* d_in, const int* in_sizes, int n_in,
                              void* d_out, int out_size, void* d_ws, size_t ws_size,
                              hipStream_t stream) {
  const float* x     = (const float*)d_in[0];
  const float* Wqkv  = (const float*)d_in[1];
  const float* bqkv  = (const float*)d_in[2];
  const float* Wproj = (const float*)d_in[3];
  const float* bproj = (const float*)d_in[4];
  float* out = (float*)d_out;

  char* ws = (char*)d_ws;
  // byte offsets (256-aligned); total ~127 MB
  unsigned short* qkv_bf   = (unsigned short*)(ws);                 // 75,497,472 B  (row-major)
  unsigned short* x_swz    = (unsigned short*)(ws + 75497472);      // 25,165,824 B  (swizzled)
  unsigned short* attn_swz = (unsigned short*)(ws + 100663296);     // 25,165,824 B  (swizzled)
  unsigned short* wqkv_swz = (unsigned short*)(ws + 125829120);     //    884,736 B  (swizzled)
  unsigned short* wproj_swz= (unsigned short*)(ws + 126713856);     //    294,912 B  (swizzled)

  // converts into swizzled fragment-major layout (all have K=384, sizes divide 256 chunks)
  cvt_swz<DIM><<<ROWS * (DIM / 8) / 256, 256, 0, stream>>>(x, x_swz);
  cvt_swz<DIM><<<QKV_CH * (DIM / 8) / 256, 256, 0, stream>>>(Wqkv, wqkv_swz);
  cvt_swz<DIM><<<DIM * (DIM / 8) / 256, 256, 0, stream>>>(Wproj, wproj_swz);

  // qkv = x @ Wqkv^T + bqkv   (bf16 row-major out)
  gemm_swz<1, DIM, QKV_CH><<<dim3(ROWS / 128, QKV_CH / 128), 256, 0, stream>>>(
      x_swz, wqkv_swz, bqkv, (void*)qkv_bf);

  // dilated attention (swizzled bf16 out)
  attn_kernel<<<ROWS / 16, 192, 0, stream>>>(qkv_bf, attn_swz);

  // out = attn @ Wproj^T + bproj  (fp32 row-major out)
  gemm_swz<0, DIM, DIM><<<dim3(ROWS / 128, DIM / 128), 256, 0, stream>>>(
      attn_swz, wproj_swz, bproj, (void*)out);
}

// Round 5
// 170.203 us; speedup vs baseline: 1.6536x; 1.2427x over previous
//
#include <hip/hip_runtime.h>

// ---------------- problem constants ----------------
#define DIM     384
#define QKV_CH  1152          // 3*DIM
#define HD      32            // head dim
#define CD      128           // channels per dilation group (4 heads)
#define BATCH   4
#define SEQ     8192
#define ROWS    (BATCH*SEQ)   // 32768
#define SCALE   0.17677669529663687f   // 32^-0.5

#define KB8         48            // K/8 for K=384
#define FRAG_STRIDE (KB8*128)     // 6144 shorts per 16-row block in swizzled layout
#define XRB_MAX     (ROWS/16 - 1) // 2047
#define LSTR        136           // LDS tile row stride in shorts (272B: 8B and 16B aligned)

typedef short bf16x8 __attribute__((ext_vector_type(8)));
typedef float f32x4  __attribute__((ext_vector_type(4)));

__device__ __forceinline__ unsigned short f2bf(float f) {
  unsigned int u = __float_as_uint(f);
  u += 0x7fffu + ((u >> 16) & 1u);      // RNE
  return (unsigned short)(u >> 16);
}
__device__ __forceinline__ float bf2f(unsigned short b) {
  return __uint_as_float(((unsigned int)b) << 16);
}
__device__ __forceinline__ void unpack4(uint2 u, float* f) {
  f[0] = bf2f((unsigned short)(u.x & 0xffffu)); f[1] = bf2f((unsigned short)(u.x >> 16));
  f[2] = bf2f((unsigned short)(u.y & 0xffffu)); f[3] = bf2f((unsigned short)(u.y >> 16));
}

// ================= swizzled (fragment-major) layout =================
// swz(r,k; K=384) = ((r/16)*48 + k/8)*128 + (r%16)*8 + (k%8)
// MFMA fragment (16 rows x 32 k) = base + lane*8 shorts, one coalesced 1KB wave load.

// ---------------- fp32 -> swizzled bf16 convert ----------------
template<int K>
__global__ __launch_bounds__(256) void cvt_swz(const float* __restrict__ in,
                                               unsigned short* __restrict__ out) {
  const int KB = K / 8;
  int cid = blockIdx.x * 256 + threadIdx.x;
  int rl = cid & 15;
  int q  = cid >> 4;
  int rb = q / KB;
  int kb = q - rb * KB;
  const float* p = in + (size_t)(rb * 16 + rl) * K + kb * 8;
  float4 a = *(const float4*)p;
  float4 b = *(const float4*)(p + 4);
  unsigned int w0 = (unsigned int)f2bf(a.x) | ((unsigned int)f2bf(a.y) << 16);
  unsigned int w1 = (unsigned int)f2bf(a.z) | ((unsigned int)f2bf(a.w) << 16);
  unsigned int w2 = (unsigned int)f2bf(b.x) | ((unsigned int)f2bf(b.y) << 16);
  unsigned int w3 = (unsigned int)f2bf(b.z) | ((unsigned int)f2bf(b.w) << 16);
  uint4 u; u.x = w0; u.y = w1; u.z = w2; u.w = w3;
  *(uint4*)(out + (size_t)cid * 8) = u;
}

// ---------------- bf16 MFMA GEMM (register-direct, swizzled inputs) ----------------
template<int OUT_BF16, int K, int NT>
__global__ __launch_bounds__(256) void gemm_swz(const unsigned short* __restrict__ A,
                                                const unsigned short* __restrict__ Bt,
                                                const float* __restrict__ bias,
                                                void* __restrict__ Cv) {
  const int KB = K / 8;
  const int t = threadIdx.x;
  const int wave = t >> 6, lane = t & 63;
  const int quad = lane >> 4, l16 = lane & 15;
  const int row0 = blockIdx.x * 128, col0 = blockIdx.y * 128;
  const int wm = (wave & 1) * 64, wn = (wave >> 1) * 64;

  const unsigned short* PA[4];
  const unsigned short* PB[4];
#pragma unroll
  for (int mi = 0; mi < 4; ++mi)
    PA[mi] = A + (size_t)(((row0 + wm) >> 4) + mi) * KB * 128 + lane * 8;
#pragma unroll
  for (int ni = 0; ni < 4; ++ni)
    PB[ni] = Bt + (size_t)(((col0 + wn) >> 4) + ni) * KB * 128 + lane * 8;

  f32x4 acc[4][4] = {};

#pragma unroll
  for (int kk = 0; kk < K / 32; ++kk) {
    bf16x8 af[4], bfv[4];
#pragma unroll
    for (int mi = 0; mi < 4; ++mi) af[mi]  = *(const bf16x8*)(PA[mi] + kk * 512);
#pragma unroll
    for (int ni = 0; ni < 4; ++ni) bfv[ni] = *(const bf16x8*)(PB[ni] + kk * 512);
#pragma unroll
    for (int mi = 0; mi < 4; ++mi)
#pragma unroll
      for (int ni = 0; ni < 4; ++ni)
        acc[mi][ni] = __builtin_amdgcn_mfma_f32_16x16x32_bf16(bfv[ni], af[mi], acc[mi][ni], 0, 0, 0);
  }

  float4 bv[4];
#pragma unroll
  for (int ni = 0; ni < 4; ++ni)
    bv[ni] = *(const float4*)&bias[col0 + wn + ni * 16 + quad * 4];

#pragma unroll
  for (int mi = 0; mi < 4; ++mi) {
    size_t gr = (size_t)(row0 + wm + mi * 16 + l16);
#pragma unroll
    for (int ni = 0; ni < 4; ++ni) {
      int gc = col0 + wn + ni * 16 + quad * 4;
      float v0 = acc[mi][ni][0] + bv[ni].x;
      float v1 = acc[mi][ni][1] + bv[ni].y;
      float v2 = acc[mi][ni][2] + bv[ni].z;
      float v3 = acc[mi][ni][3] + bv[ni].w;
      if (OUT_BF16) {
        uint2 u;
        u.x = (unsigned int)f2bf(v0) | ((unsigned int)f2bf(v1) << 16);
        u.y = (unsigned int)f2bf(v2) | ((unsigned int)f2bf(v3) << 16);
        *(uint2*)&((unsigned short*)Cv)[gr * NT + gc] = u;
      } else {
        float4 o; o.x = v0; o.y = v1; o.z = v2; o.w = v3;
        *(float4*)&((float*)Cv)[gr * NT + gc] = o;
      }
    }
  }
}

// ---------------- fused QKV-projection + dilated attention ----------------
// Block = (64-row tile, dilation group d). Computes q (64x128), k,v (96x128 with
// +-16-row halo) from x_swz and the group's wqkv columns via register-direct MFMA,
// stages bf16 tiles in LDS, then 64 rows x 4 heads of 3-tap softmax-attention,
// writing attn output straight to global in swizzled layout. qkv never hits HBM.
__global__ __launch_bounds__(256, 2) void fused_qkv_attn(
    const unsigned short* __restrict__ X,     // x_swz    [ROWS,384] swizzled
    const unsigned short* __restrict__ W,     // wqkv_swz [1152,384] swizzled
    const float* __restrict__ bqkv,           // [1152]
    unsigned short* __restrict__ out) {       // attn_swz [ROWS,384] swizzled
  __shared__ unsigned short sm[34816];        // 69632 B
  unsigned short* q_t = sm;                   // 64 rows x LSTR
  unsigned short* k_t = sm + 64 * LSTR;       // 96 rows x LSTR (rows row0-16..row0+80)
  unsigned short* v_t = sm + 160 * LSTR;      // 96 rows x LSTR

  const int t = threadIdx.x;
  const int w = t >> 6, lane = t & 63;
  const int quad = lane >> 4, l16 = lane & 15;
  const int d = blockIdx.y;
  const int row0 = blockIdx.x * 64;
  const int rb0 = row0 >> 4;

  // ---- phase 1: MFMA. wave w owns output cols w*32..w*32+32 (2 col-blocks)
  // for ALL row-blocks of q (4), k (6), v (6). k/v reuse q's x-fragments.
  const unsigned short* pa[6];
#pragma unroll
  for (int j = 0; j < 6; ++j) {
    int xrb = rb0 - 1 + j;                         // halo row-blocks, clamped at
    xrb = xrb < 0 ? 0 : (xrb > XRB_MAX ? XRB_MAX : xrb);  // global edges (unused taps)
    pa[j] = X + (size_t)xrb * FRAG_STRIDE + lane * 8;
  }
  const unsigned short *pbq[2], *pbk[2], *pbv[2];
#pragma unroll
  for (int c = 0; c < 2; ++c) {
    int wrb = d * 8 + w * 2 + c;                   // weight row-block (channel/16)
    pbq[c] = W + (size_t)wrb * FRAG_STRIDE + lane * 8;
    pbk[c] = W + (size_t)(wrb + 24) * FRAG_STRIDE + lane * 8;
    pbv[c] = W + (size_t)(wrb + 48) * FRAG_STRIDE + lane * 8;
  }

  f32x4 aq[4][2] = {}, ak[6][2] = {}, av[6][2] = {};

#pragma unroll
  for (int kk = 0; kk < 12; ++kk) {
    bf16x8 a[6];
#pragma unroll
    for (int j = 0; j < 6; ++j) a[j] = *(const bf16x8*)(pa[j] + kk * 512);
    bf16x8 bq[2], bk[2], bv[2];
#pragma unroll
    for (int c = 0; c < 2; ++c) {
      bq[c] = *(const bf16x8*)(pbq[c] + kk * 512);
      bk[c] = *(const bf16x8*)(pbk[c] + kk * 512);
      bv[c] = *(const bf16x8*)(pbv[c] + kk * 512);
    }
#pragma unroll
    for (int c = 0; c < 2; ++c) {
#pragma unroll
      for (int j = 0; j < 4; ++j)
        aq[j][c] = __builtin_amdgcn_mfma_f32_16x16x32_bf16(bq[c], a[j + 1], aq[j][c], 0, 0, 0);
#pragma unroll
      for (int j = 0; j < 6; ++j)
        ak[j][c] = __builtin_amdgcn_mfma_f32_16x16x32_bf16(bk[c], a[j], ak[j][c], 0, 0, 0);
#pragma unroll
      for (int j = 0; j < 6; ++j)
        av[j][c] = __builtin_amdgcn_mfma_f32_16x16x32_bf16(bv[c], a[j], av[j][c], 0, 0, 0);
    }
  }

  // ---- epilogue: bias + bf16 + LDS stage. lane holds row l16, cols quad*4+reg.
#pragma unroll
  for (int c = 0; c < 2; ++c) {
    int colb = w * 32 + c * 16 + quad * 4;
    float4 b_q = *(const float4*)&bqkv[d * CD + colb];
    float4 b_k = *(const float4*)&bqkv[384 + d * CD + colb];
    float4 b_v = *(const float4*)&bqkv[768 + d * CD + colb];
#pragma unroll
    for (int j = 0; j < 4; ++j) {
      uint2 u;
      u.x = (unsigned int)f2bf(aq[j][c][0] + b_q.x) | ((unsigned int)f2bf(aq[j][c][1] + b_q.y) << 16);
      u.y = (unsigned int)f2bf(aq[j][c][2] + b_q.z) | ((unsigned int)f2bf(aq[j][c][3] + b_q.w) << 16);
      *(uint2*)&q_t[(j * 16 + l16) * LSTR + colb] = u;
    }
#pragma unroll
    for (int j = 0; j < 6; ++j) {
      uint2 u;
      u.x = (unsigned int)f2bf(ak[j][c][0] + b_k.x) | ((unsigned int)f2bf(ak[j][c][1] + b_k.y) << 16);
      u.y = (unsigned int)f2bf(ak[j][c][2] + b_k.z) | ((unsigned int)f2bf(ak[j][c][3] + b_k.w) << 16);
      *(uint2*)&k_t[(j * 16 + l16) * LSTR + colb] = u;
    }
#pragma unroll
    for (int j = 0; j < 6; ++j) {
      uint2 u;
      u.x = (unsigned int)f2bf(av[j][c][0] + b_v.x) | ((unsigned int)f2bf(av[j][c][1] + b_v.y) << 16);
      u.y = (unsigned int)f2bf(av[j][c][2] + b_v.z) | ((unsigned int)f2bf(av[j][c][3] + b_v.w) << 16);
      *(uint2*)&v_t[(j * 16 + l16) * LSTR + colb] = u;
    }
  }
  __syncthreads();

  // ---- phase 2: attention. thread = (head h = wave, row r = lane..) over 64 rows.
  const int h = t >> 6;
  const int r = t & 63;
  const int dil = d + 1;
  const int n = (row0 + r) & (SEQ - 1);

  float q[32];
  {
    const uint2* qp = (const uint2*)&q_t[r * LSTR + h * HD];
#pragma unroll
    for (int c = 0; c < 8; ++c) unpack4(qp[c], &q[c * 4]);
  }

  float ex[3];
  int   valid[3];
#pragma unroll
  for (int kh = 0; kh < 3; ++kh) {
    int off = (kh - 1) * dil;
    int nn = n + off;
    int v = (nn >= 0) && (nn < SEQ);
    valid[kh] = v;
    float l = 0.f;
    if (v) {
      const uint2* kp = (const uint2*)&k_t[(r + 16 + off) * LSTR + h * HD];
#pragma unroll
      for (int c = 0; c < 8; ++c) {
        float kkv[4]; unpack4(kp[c], kkv);
#pragma unroll
        for (int j = 0; j < 4; ++j) l += q[c * 4 + j] * kkv[j];
      }
    }
    ex[kh] = v ? __expf(l * SCALE) : 1.f;   // zero-padded tap -> exp(0)=1
  }
  float inv = 1.f / (ex[0] + ex[1] + ex[2] + 6.f);  // +6 structural zero taps

  float o[32];
#pragma unroll
  for (int e = 0; e < 32; ++e) o[e] = 0.f;
#pragma unroll
  for (int kh = 0; kh < 3; ++kh) {
    if (!valid[kh]) continue;
    int off = (kh - 1) * dil;
    const uint2* vp = (const uint2*)&v_t[(r + 16 + off) * LSTR + h * HD];
    float wgt = ex[kh];
#pragma unroll
    for (int c = 0; c < 8; ++c) {
      float vv[4]; unpack4(vp[c], vv);
#pragma unroll
      for (int j = 0; j < 4; ++j) o[c * 4 + j] += wgt * vv[j];
    }
  }

  // swizzled global write: 4 chunks of 8 ch; 16 consecutive rows -> 256B contiguous
  int row = row0 + r;
  int ch0 = d * CD + h * HD;
  unsigned short* op = out + ((size_t)(row >> 4) * KB8 + (ch0 >> 3)) * 128 + (row & 15) * 8;
#pragma unroll
  for (int c = 0; c < 4; ++c) {
    uint4 u;
    u.x = (unsigned int)f2bf(o[c*8+0] * inv) | ((unsigned int)f2bf(o[c*8+1] * inv) << 16);
    u.y = (unsigned int)f2bf(o[c*8+2] * inv) | ((unsigned int)f2bf(o[c*8+3] * inv) << 16);
    u.z = (unsigned int)f2bf(o[c*8+4] * inv) | ((unsigned int)f2bf(o[c*8+5] * inv) << 16);
    u.w = (unsigned int)f2bf(o[c*8+6] * inv) | ((unsigned int)f2bf(o[c*8+7] * inv) << 16);
    *(uint4*)(op + c * 128) = u;
  }
}

// ---------------- launch ----------------
extern "C" void kernel_launch(void* const* d_in, const int* in_sizes, int n_in,
                              void* d_out, int out_size, void* d_ws, size_t ws_size,
                              hipStream_t stream) {
  const float* x     = (const float*)d_in[0];
  const float* Wqkv  = (const float*)d_in[1];
  const float* bqkv  = (const float*)d_in[2];
  const float* Wproj = (const float*)d_in[3];
  const float* bproj = (const float*)d_in[4];
  float* out = (float*)d_out;

  char* ws = (char*)d_ws;
  unsigned short* x_swz     = (unsigned short*)(ws);                // 25,165,824 B
  unsigned short* attn_swz  = (unsigned short*)(ws + 25165824);     // 25,165,824 B
  unsigned short* wqkv_swz  = (unsigned short*)(ws + 50331648);     //    884,736 B
  unsigned short* wproj_swz = (unsigned short*)(ws + 51216384);     //    294,912 B

  // converts into swizzled fragment-major layout
  cvt_swz<DIM><<<ROWS * (DIM / 8) / 256, 256, 0, stream>>>(x, x_swz);
  cvt_swz<DIM><<<QKV_CH * (DIM / 8) / 256, 256, 0, stream>>>(Wqkv, wqkv_swz);
  cvt_swz<DIM><<<DIM * (DIM / 8) / 256, 256, 0, stream>>>(Wproj, wproj_swz);

  // fused qkv-projection + dilated attention (qkv never hits HBM)
  fused_qkv_attn<<<dim3(ROWS / 64, 3), 256, 0, stream>>>(x_swz, wqkv_swz, bqkv, attn_swz);

  // out = attn @ Wproj^T + bproj  (fp32 row-major out)
  gemm_swz<0, DIM, DIM><<<dim3(ROWS / 128, DIM / 128), 256, 0, stream>>>(
      attn_swz, wproj_swz, bproj, (void*)out);
}